// Round 2
// baseline (740.910 us; speedup 1.0000x reference)
//
#include <hip/hip_runtime.h>
#include <math.h>

#define N_NODES 100000
#define N_EDGES 3200000
#define NH 16            // channels per stack
#define SST (N_NODES * NH)  // per-stack element stride in t/h buffers
#define BN_EPS 1e-5f
#define NBUCK 196        // ceil(100000/512) buckets of 512 nodes
#define BSHIFT 9
#define BMASK 511
#define EPB 16384        // edges per block in bucket scatter
#define NBLK1 196        // ceil(N_EDGES/EPB)
#define CAP 18432        // fixed bucket capacity: mean 16327 + 16 sigma
#define FIX 16777216.0f  // 2^24 fixed point for degree sums
#define NBLKS 6250       // blocks per stack in conv1_prop
#define NWAVES 25000     // waves per stack (4 nodes/wave)

typedef unsigned long long u64;
typedef unsigned int u32;
typedef unsigned short u16;
typedef __attribute__((ext_vector_type(4))) unsigned int u32x4;
typedef __attribute__((ext_vector_type(2))) unsigned int u32x2;

__device__ __forceinline__ u16 f2bf(float f) {
  u32 b = __float_as_uint(f);
  b += 0x7FFFu + ((b >> 16) & 1u);   // RNE
  return (u16)(b >> 16);
}
__device__ __forceinline__ float bf2f(u32 s) {
  return __uint_as_float(s << 16);
}

// ---------------- K1: scatter edges into FIXED-CAPACITY buckets -------------
__global__ __launch_bounds__(1024) void bucket_scatter_kernel(
    const int* __restrict__ row, const int* __restrict__ col,
    const float* __restrict__ ea, u32* __restrict__ gcur,
    int2* __restrict__ bucketed) {
  __shared__ u32 bins[NBUCK];
  __shared__ u32 base[NBUCK];
  __shared__ u16 rnk[EPB];
  for (int t = threadIdx.x; t < NBUCK; t += 1024) bins[t] = 0;
  __syncthreads();
  int eb = blockIdx.x * EPB;
  for (int it = 0; it < EPB / 1024; ++it) {
    int i = it * 1024 + threadIdx.x;
    int e = eb + i;
    if (e < N_EDGES) rnk[i] = (u16)atomicAdd(&bins[col[e] >> BSHIFT], 1u);
  }
  __syncthreads();
  for (int t = threadIdx.x; t < NBUCK; t += 1024) {
    u32 c = bins[t];
    if (c) base[t] = (u32)t * CAP + atomicAdd(&gcur[t * 8], c);
  }
  __syncthreads();
  for (int it = 0; it < EPB / 1024; ++it) {
    int i = it * 1024 + threadIdx.x;
    int e = eb + i;
    if (e < N_EDGES) {
      int c = col[e];
      int bkt = c >> BSHIFT, cl = c & BMASK;
      u32 pos = base[bkt] + (u32)rnk[i];
      bucketed[pos] = make_int2((cl << 17) | row[e], __float_as_int(ea[e]));
    }
  }
}

// ---------------- P2a: per-bucket node counts -> offs, dinv, zx -------------
__global__ __launch_bounds__(1024) void node_offs_kernel(
    const int2* __restrict__ bucketed, const u32* __restrict__ gcur,
    const float* __restrict__ x,
    int* __restrict__ offs, float* __restrict__ dinv, u16* __restrict__ zx) {
  __shared__ u32 cnt[512];
  __shared__ u32 degf[512];
  __shared__ u32 red[256];
  __shared__ u32 shmeta[2];   // [0]=bstart, [1]=fill
  int t = threadIdx.x;
  int b = blockIdx.x;
  if (t < 512) { cnt[t] = 0; degf[t] = 0; }
  if (t < 256) red[t] = (t < b) ? gcur[t * 8] : 0;   // NBUCK<256
  __syncthreads();
  for (int d = 128; d; d >>= 1) {
    if (t < d) red[t] += red[t + d];
    __syncthreads();
  }
  if (t == 0) { shmeta[0] = red[0]; shmeta[1] = gcur[b * 8]; }
  __syncthreads();
  u32 bst = shmeta[0], fill = shmeta[1];
  u32 s_pad = (u32)b * CAP;
  for (u32 i = t; i < fill; i += 1024) {
    int2 v = bucketed[s_pad + i];
    int cl = (v.x >> 17) & BMASK;
    atomicAdd(&cnt[cl], 1u);
    atomicAdd(&degf[cl], (u32)(__int_as_float(v.y) * FIX));
  }
  __syncthreads();
  u32 v0 = (t < 512) ? cnt[t] : 0;
  for (int d = 1; d < 512; d <<= 1) {
    u32 u = (t < 512 && t >= d) ? cnt[t - d] : 0;
    __syncthreads();
    if (t < 512) cnt[t] += u;
    __syncthreads();
  }
  int n = b * 512 + t;
  if (t < 512 && n < N_NODES) {
    offs[n] = (int)(bst + cnt[t] - v0);  // exclusive, compact
    float dg = (float)degf[t] * (1.0f / FIX);
    float dv = dg > 0.f ? rsqrtf(fmaxf(dg, 1e-12f)) : 0.f;
    dinv[n] = dv;
    zx[n] = f2bf(x[n] * dv);
  }
  if (b == 0 && t == 0) offs[N_NODES] = N_EDGES;
}

// ---------------- P2b: packed 4B CSR: (src<<15) | bf16(ea) ------------------
__global__ __launch_bounds__(1024) void csr_fill_kernel(
    const int2* __restrict__ bucketed, const u32* __restrict__ gcur,
    const int* __restrict__ offs, u32* __restrict__ csr) {
  __shared__ u32 cur[512];
  __shared__ u32 shfill;
  int t = threadIdx.x;
  int b = blockIdx.x;
  int n = b * 512 + t;
  if (t < 512) cur[t] = (n < N_NODES) ? (u32)offs[n] : 0;
  if (t == 0) shfill = gcur[b * 8];
  __syncthreads();
  u32 fill = shfill;
  u32 s_pad = (u32)b * CAP;
  for (u32 i = t; i < fill; i += 1024) {
    int2 v = bucketed[s_pad + i];
    int cl = (v.x >> 17) & BMASK;
    u32 r = (u32)(v.x & 0x1FFFF);
    u16 w = f2bf(__int_as_float(v.y));   // ea >= 0 -> sign bit 0, w < 0x8000
    u32 pos = atomicAdd(&cur[cl], 1u);
    csr[pos] = (r << 15) | (u32)w;
  }
}

// ---------------- layer-1: scalar prop + epilogue + transform (merged) ------
// Writes tout in per-stack layout: [K][N][16]
__global__ __launch_bounds__(256) void sprop_mid_kernel(
    const u32* __restrict__ csr, const int* __restrict__ offs,
    const u16* __restrict__ zx, const float* __restrict__ dinv,
    const float* __restrict__ x,
    const float* __restrict__ w1i, const float* __restrict__ w1r,
    const float* __restrict__ b1, const float* __restrict__ w1,
    u16* __restrict__ tout) {
  int t = blockIdx.x * 256 + threadIdx.x;
  int n = t >> 4, c = t & 15;
  float a = 0.f;
  int s = offs[n], e = offs[n + 1];
  for (int i = s + c; i < e; i += 16) {
    u32 ee = csr[i];
    a += bf2f(ee & 0x7FFFu) * bf2f((u32)zx[ee >> 15]);
  }
#pragma unroll
  for (int o = 8; o; o >>= 1) a += __shfl_xor(a, o, 64);
  float dn = dinv[n];
  float sn = a * dn;
  float xn = x[n];
  int base = (threadIdx.x & 63) & 48;
#pragma unroll
  for (int k = 0; k < 3; ++k) {
    float u = fmaxf(sn * w1i[k * 16 + c] + xn * w1r[k * 16 + c] + b1[k * 16 + c], 0.f);
    float tf = 0.f;
#pragma unroll
    for (int f = 0; f < 16; ++f) tf += __shfl(u, base + f, 64) * w1[k * 256 + f * 16 + c];
    tout[(size_t)k * SST + (size_t)n * NH + c] = f2bf(tf * dn);
  }
}

// ---------------- conv1 propagate: PER-STACK, k-partitioned grid ------------
// wave = 4 sub-groups x 16 channels; each sub-group gathers one 32 B row
// (4 edges per VMEM instr). Per-stack table = 3.2 MB -> L2-resident per XCD.
__global__ __launch_bounds__(256) void conv1_prop_kernel(
    const u16* __restrict__ tin, u16* __restrict__ tout, float* __restrict__ hbuf3,
    const u32* __restrict__ csr, const int* __restrict__ offs,
    const float* __restrict__ dinv, const float* __restrict__ x,
    const float* __restrict__ w1r, const float* __restrict__ b1,
    const float* __restrict__ w1, int do_t) {
  int k = blockIdx.x / NBLKS;
  int bid = blockIdx.x - k * NBLKS;
  int lane = threadIdx.x & 63;
  int sub = lane >> 4;
  int c = lane & 15;
  int wid = ((bid << 8) + (int)threadIdx.x) >> 6;   // 0..NWAVES-1 within stack
  const u16* __restrict__ tk = tin + (size_t)k * SST;
  float rb = w1r[k * NH + c];
  float bb = b1[k * NH + c];
  int srcbase = sub * 20;    // = sub*16 (group base) + sub*4 (f offset)
  float wreg[4];
  if (do_t) {
#pragma unroll
    for (int j = 0; j < 4; ++j) wreg[j] = w1[k * 256 + (sub * 4 + j) * NH + c];
  }
  for (int n = wid; n < N_NODES; n += NWAVES) {
    int nu = __builtin_amdgcn_readfirstlane(n);
    int s = offs[nu], e = offs[nu + 1];
    float dn = dinv[nu];
    float xn = x[nu];
    float acc = 0.f;
    int i = s;
    // masked lead: align i to a multiple of 4 for dwordx4/dwordx2 tiers
    int la = (4 - (i & 3)) & 3;
    if (la > e - i) la = e - i;
    if (sub < la) {
      u32 ee = __builtin_nontemporal_load(csr + i + sub);
      acc += bf2f(ee & 0x7FFFu) * bf2f((u32)tk[(ee >> 15) * NH + c]);
    }
    i += la;
    // 16-edge tier: one dwordx4 csr load per lane, 4 gathers
    for (; i + 16 <= e; i += 16) {
      u32x4 q = __builtin_nontemporal_load((const u32x4*)(csr + i) + sub);
      acc += bf2f(q.x & 0x7FFFu) * bf2f((u32)tk[(q.x >> 15) * NH + c]);
      acc += bf2f(q.y & 0x7FFFu) * bf2f((u32)tk[(q.y >> 15) * NH + c]);
      acc += bf2f(q.z & 0x7FFFu) * bf2f((u32)tk[(q.z >> 15) * NH + c]);
      acc += bf2f(q.w & 0x7FFFu) * bf2f((u32)tk[(q.w >> 15) * NH + c]);
    }
    // 8-edge tier
    for (; i + 8 <= e; i += 8) {
      u32x2 q = __builtin_nontemporal_load((const u32x2*)(csr + i) + sub);
      acc += bf2f(q.x & 0x7FFFu) * bf2f((u32)tk[(q.x >> 15) * NH + c]);
      acc += bf2f(q.y & 0x7FFFu) * bf2f((u32)tk[(q.y >> 15) * NH + c]);
    }
    // 4-edge tier
    for (; i + 4 <= e; i += 4) {
      u32 ee = __builtin_nontemporal_load(csr + i + sub);
      acc += bf2f(ee & 0x7FFFu) * bf2f((u32)tk[(ee >> 15) * NH + c]);
    }
    // masked tail (0..3 edges)
    int rem = e - i;
    if (sub < rem) {
      u32 ee = __builtin_nontemporal_load(csr + i + sub);
      acc += bf2f(ee & 0x7FFFu) * bf2f((u32)tk[(ee >> 15) * NH + c]);
    }
    // reduce the 4 sub-groups
    acc += __shfl_xor(acc, 16, 64);
    acc += __shfl_xor(acc, 32, 64);
    float u = fmaxf(acc * dn + xn * rb + bb, 0.f);
    if (do_t) {
      // split 16x16 transform across sub-groups: 4 partial FMAs + 2 xor-reduce
      float tf = 0.f;
#pragma unroll
      for (int j = 0; j < 4; ++j) tf += __shfl(u, srcbase + j, 64) * wreg[j];
      tf += __shfl_xor(tf, 16, 64);
      tf += __shfl_xor(tf, 32, 64);
      if (sub == 0) tout[(size_t)k * SST + (size_t)nu * NH + c] = f2bf(tf * dn);
    } else {
      if (sub == 0) hbuf3[(size_t)k * SST + (size_t)nu * NH + c] = u;
    }
  }
}

// ---------------- BN stats over hbuf3 [3][N,16]: stats of per-node mean -----
__global__ __launch_bounds__(256) void bn_stats_kernel(
    const float* __restrict__ h, double* __restrict__ stats) {
  __shared__ float ssum[NH], ssq[NH];
  int tid = threadIdx.x;
  if (tid < NH) { ssum[tid] = 0.f; ssq[tid] = 0.f; }
  __syncthreads();
  int n = blockIdx.x * blockDim.x + tid;
  bool valid = n < N_NODES;
  size_t base = (size_t)(valid ? n : 0) * NH;
  const float4* p0 = (const float4*)(h + base);
  const float4* p1 = (const float4*)(h + (size_t)SST + base);
  const float4* p2 = (const float4*)(h + 2 * (size_t)SST + base);
  float hv[NH];
#pragma unroll
  for (int q = 0; q < 4; ++q) {
    float4 a = valid ? p0[q] : make_float4(0.f, 0.f, 0.f, 0.f);
    float4 b = valid ? p1[q] : make_float4(0.f, 0.f, 0.f, 0.f);
    float4 d = valid ? p2[q] : make_float4(0.f, 0.f, 0.f, 0.f);
    hv[q * 4 + 0] = (a.x + b.x + d.x) * (1.f / 3.f);
    hv[q * 4 + 1] = (a.y + b.y + d.y) * (1.f / 3.f);
    hv[q * 4 + 2] = (a.z + b.z + d.z) * (1.f / 3.f);
    hv[q * 4 + 3] = (a.w + b.w + d.w) * (1.f / 3.f);
  }
#pragma unroll
  for (int f = 0; f < NH; ++f) {
    float s = hv[f], q = hv[f] * hv[f];
    for (int o = 32; o; o >>= 1) { s += __shfl_xor(s, o, 64); q += __shfl_xor(q, o, 64); }
    if ((tid & 63) == 0) { atomicAdd(&ssum[f], s); atomicAdd(&ssq[f], q); }
  }
  __syncthreads();
  if (tid < NH) {
    atomicAdd(&stats[tid], (double)ssum[tid]);
    atomicAdd(&stats[NH + tid], (double)ssq[tid]);
  }
}

__global__ __launch_bounds__(64) void bn_final_kernel(
    const double* __restrict__ stats, const float* __restrict__ g,
    const float* __restrict__ b, float* __restrict__ sc, float* __restrict__ sh) {
  int f = threadIdx.x;
  if (f < NH) {
    double mu = stats[f] / (double)N_NODES;
    double var = stats[NH + f] / (double)N_NODES - mu * mu;
    float scale = g[f] * (float)(1.0 / sqrt(var + (double)BN_EPS));
    sc[f] = scale;
    sh[f] = b[f] - (float)mu * scale;
  }
}

// ---------------- conv2 init: mean over k + BN-apply + relu + init/root -----
__global__ __launch_bounds__(256) void conv2_init_kernel(
    const float* __restrict__ h, const float* __restrict__ sc, const float* __restrict__ sh,
    const float* __restrict__ dinv,
    const float* __restrict__ w2i, const float* __restrict__ w2r, const float* __restrict__ b2,
    float* __restrict__ P, float* __restrict__ R) {
  int n = blockIdx.x * blockDim.x + threadIdx.x;
  if (n >= N_NODES) return;
  size_t base = (size_t)n * NH;
  float u[NH];
#pragma unroll
  for (int f = 0; f < NH; ++f) {
    float m = (h[base + f] + h[(size_t)SST + base + f] + h[2 * (size_t)SST + base + f]) * (1.f / 3.f);
    u[f] = fmaxf(m * sc[f] + sh[f], 0.f);
  }
  float dn = dinv[n];
#pragma unroll
  for (int k = 0; k < 3; ++k) {
    float r = b2[k], o = 0.f;
#pragma unroll
    for (int f = 0; f < NH; ++f) {
      r += u[f] * w2r[k * NH + f];
      o += u[f] * w2i[k * NH + f];
    }
    R[n * 4 + k] = r;
    P[n * 4 + k] = o * dn;
  }
  R[n * 4 + 3] = 0.f;
  P[n * 4 + 3] = 0.f;
}

// ---------------- conv2 propagate: 16-lane groups, packed CSR ---------------
__global__ __launch_bounds__(256) void conv2_prop_kernel(
    const float* __restrict__ in4, float* __restrict__ out4, float* __restrict__ y,
    const u32* __restrict__ csr, const int* __restrict__ offs,
    const float* __restrict__ dinv,
    const float* __restrict__ R, const float* __restrict__ w2,
    int scale_w2, int final_out) {
  int t = blockIdx.x * 256 + threadIdx.x;
  int n = t >> 4, sub = t & 15;
  float m0 = 1.f, m1 = 1.f, m2 = 1.f;
  if (scale_w2) { m0 = w2[0]; m1 = w2[1]; m2 = w2[2]; }
  int s = offs[n], e = offs[n + 1];
  float a0 = 0.f, a1 = 0.f, a2 = 0.f;
  for (int i = s + sub; i < e; i += 16) {
    u32 ee = csr[i];
    float w = bf2f(ee & 0x7FFFu);
    const float4 v = *(const float4*)(in4 + (size_t)(ee >> 15) * 4);
    a0 += w * v.x;
    a1 += w * v.y;
    a2 += w * v.z;
  }
#pragma unroll
  for (int o = 8; o; o >>= 1) {
    a0 += __shfl_xor(a0, o, 64);
    a1 += __shfl_xor(a1, o, 64);
    a2 += __shfl_xor(a2, o, 64);
  }
  if (sub == 0) {
    float dn = dinv[n];
    a0 = a0 * dn * m0 + R[n * 4 + 0];
    a1 = a1 * dn * m1 + R[n * 4 + 1];
    a2 = a2 * dn * m2 + R[n * 4 + 2];
    if (final_out) {
      float sm = (a0 + a1 + a2) * (1.f / 3.f);
      y[n] = 1.f / (1.f + expf(-sm));
    } else {
      out4[n * 4 + 0] = a0 * dn;
      out4[n * 4 + 1] = a1 * dn;
      out4[n * 4 + 2] = a2 * dn;
      out4[n * 4 + 3] = 0.f;
    }
  }
}

extern "C" void kernel_launch(void* const* d_in, const int* in_sizes, int n_in,
                              void* d_out, int out_size, void* d_ws, size_t ws_size,
                              hipStream_t stream) {
  const float* x   = (const float*)d_in[0];
  const int*   ei  = (const int*)d_in[1];
  const float* ea  = (const float*)d_in[2];
  // d_in[3] = batch (unused)
  const float* w1i = (const float*)d_in[4];
  const float* w1  = (const float*)d_in[5];
  const float* w1r = (const float*)d_in[6];
  const float* b1  = (const float*)d_in[7];
  const float* bng = (const float*)d_in[8];
  const float* bnb = (const float*)d_in[9];
  const float* w2i = (const float*)d_in[10];
  const float* w2  = (const float*)d_in[11];
  const float* w2r = (const float*)d_in[12];
  const float* b2  = (const float*)d_in[13];
  float* y = (float*)d_out;

  const int* row = ei;
  const int* col = ei + N_EDGES;

  char* ws = (char*)d_ws;
  size_t off = 0;
  auto alloc = [&](size_t bytes) -> char* {
    char* p = ws + off;
    off += (bytes + 255) & ~(size_t)255;
    return p;
  };
  u32*    gcur   = (u32*)alloc((size_t)NBUCK * 8 * 4);
  int*    offs   = (int*)alloc((size_t)(N_NODES + 1) * 4);
  float*  dinv   = (float*)alloc((size_t)N_NODES * 4);
  u16*    zx     = (u16*)alloc((size_t)N_NODES * 2);
  double* stats  = (double*)alloc(32 * 8);
  float*  bnsc   = (float*)alloc(16 * 4);
  float*  bnsh   = (float*)alloc(16 * 4);
  int2*   bucketed = (int2*)alloc((size_t)NBUCK * CAP * 8);
  u32*    csr    = (u32*)alloc((size_t)N_EDGES * 4);
  u16*    tA     = (u16*)alloc((size_t)3 * SST * 2);
  u16*    tB     = (u16*)alloc((size_t)3 * SST * 2);
  float*  hbuf   = (float*)alloc((size_t)3 * SST * 4);
  float*  P2     = (float*)alloc((size_t)N_NODES * 4 * 4);
  float*  Q2     = (float*)alloc((size_t)N_NODES * 4 * 4);
  float*  R2     = (float*)alloc((size_t)N_NODES * 4 * 4);
  (void)ws_size; (void)in_sizes; (void)n_in; (void)out_size;

  hipMemsetAsync(gcur, 0, (size_t)NBUCK * 8 * 4, stream);
  hipMemsetAsync(stats, 0, 32 * 8, stream);

  bucket_scatter_kernel<<<NBLK1, 1024, 0, stream>>>(row, col, ea, gcur, bucketed);
  node_offs_kernel<<<NBUCK, 1024, 0, stream>>>(bucketed, gcur, x, offs, dinv, zx);
  csr_fill_kernel<<<NBUCK, 1024, 0, stream>>>(bucketed, gcur, offs, csr);

  const int NPB = 6250;  // N_NODES*16/256 exactly
  // conv1 layer 1 (rank-1 collapse): merged scalar prop + dense epilogue -> tA
  sprop_mid_kernel<<<NPB, 256, 0, stream>>>(csr, offs, zx, dinv, x, w1i, w1r, b1, w1, tA);
  // conv1 layers 2-4: per-stack propagation, k-partitioned grid (3 x 6250)
  conv1_prop_kernel<<<3 * NBLKS, 256, 0, stream>>>(tA, tB, nullptr, csr, offs, dinv, x, w1r, b1, w1, 1);
  conv1_prop_kernel<<<3 * NBLKS, 256, 0, stream>>>(tB, tA, nullptr, csr, offs, dinv, x, w1r, b1, w1, 1);
  conv1_prop_kernel<<<3 * NBLKS, 256, 0, stream>>>(tA, nullptr, hbuf, csr, offs, dinv, x, w1r, b1, w1, 0);

  bn_stats_kernel<<<(N_NODES + 255) / 256, 256, 0, stream>>>(hbuf, stats);
  bn_final_kernel<<<1, 64, 0, stream>>>(stats, bng, bnb, bnsc, bnsh);
  conv2_init_kernel<<<(N_NODES + 255) / 256, 256, 0, stream>>>(
      hbuf, bnsc, bnsh, dinv, w2i, w2r, b2, P2, R2);

  conv2_prop_kernel<<<NPB, 256, 0, stream>>>(P2, Q2, nullptr, csr, offs, dinv, R2, w2, 0, 0);
  conv2_prop_kernel<<<NPB, 256, 0, stream>>>(Q2, P2, nullptr, csr, offs, dinv, R2, w2, 1, 0);
  conv2_prop_kernel<<<NPB, 256, 0, stream>>>(P2, Q2, nullptr, csr, offs, dinv, R2, w2, 1, 0);
  conv2_prop_kernel<<<NPB, 256, 0, stream>>>(Q2, P2, y, csr, offs, dinv, R2, w2, 1, 1);
}